// Round 8
// baseline (1805.404 us; speedup 1.0000x reference)
//
#include <hip/hip_runtime.h>

#define DTF   0.001f
#define NZV   250
#define NYV   350
#define NX    294          // 250 + 44
#define NYW   394          // 350 + 44
#define PADC  22
#define NSHOT 4
#define NTS   48
#define NRECV 100
#define NCELL (NX*NYW)     // 115836
#define NTOT  (NSHOT*NCELL)
#define XBL   22           // x in [0,21] is low band
#define XBH   (NX-22)      // 272: x >= 272 is high band
#define YBH   (NYW-22)     // 372
#define NB    44
#define PXSZ  (NSHOT*NB*NYW)   // x-band state: [shot][44][NYW]
#define PYSZ  (NSHOT*NX*NB)    // y-band state: [shot][NX][44]
#define NSB   ((NTOT+255)/256) // fallback stencil blocks
#define GB    2                // fallback gather blocks
#define NTHR  256
#define NBLK  2048
#define SBLK  512              // blocks per shot partition (SBLK*NTHR >= NCELL)
#define BARF  66560            // floats reserved at ws head for barrier+vmx

// barrier layout (uint offsets into ws)
#define GFLG  0                // global flags: 2048 x 16 uints
#define GGEN  32768            // global gen line
#define VMXO  32784            // vmax accumulator
#define SFLG  33024            // shot flags: 4 x (512 x 16)
#define SSTR  8192
#define SGEN  65792            // shot gen lines: 4 x 16

// Coherence-point accesses for mutable state (resolve at fabric/L3; proven
// by r5-r7: relaxed agent flags are cross-XCD visible without fences).
__device__ __forceinline__ float ld3(const float* p) {
    return __hip_atomic_load(const_cast<float*>(p), __ATOMIC_RELAXED,
                             __HIP_MEMORY_SCOPE_AGENT);
}
__device__ __forceinline__ void st3(float* p, float v) {
    __hip_atomic_store(p, v, __ATOMIC_RELAXED, __HIP_MEMORY_SCOPE_AGENT);
}
__device__ __forceinline__ unsigned ldu(const unsigned* p) {
    return __hip_atomic_load(const_cast<unsigned*>(p), __ATOMIC_RELAXED,
                             __HIP_MEMORY_SCOPE_AGENT);
}
__device__ __forceinline__ void stu(unsigned* p, unsigned v) {
    __hip_atomic_store(p, v, __ATOMIC_RELAXED, __HIP_MEMORY_SCOPE_AGENT);
}

__device__ __forceinline__ int xbi(int i) {
    return ((unsigned)i < XBL) ? i : ((i >= XBH && i < NX) ? i-(NX-NB) : -1);
}
__device__ __forceinline__ int ybi(int j) {
    return ((unsigned)j < XBL) ? j : ((j >= YBH && j < NYW) ? j-(NYW-NB) : -1);
}
__device__ __forceinline__ float ldz(const float* __restrict__ w, int i, int j) {
    return ((unsigned)i < (unsigned)NX && (unsigned)j < (unsigned)NYW) ? ld3(&w[i*NYW + j]) : 0.f;
}
__device__ __forceinline__ float d1x(const float* __restrict__ w, int i, int j) {
    return (8.f*(ldz(w,i+1,j) - ldz(w,i-1,j)) - (ldz(w,i+2,j) - ldz(w,i-2,j))) * (1.f/60.f);
}
__device__ __forceinline__ float d1y(const float* __restrict__ w, int i, int j) {
    return (8.f*(ldz(w,i,j+1) - ldz(w,i,j-1)) - (ldz(w,i,j+2) - ldz(w,i,j-2))) * (1.f/60.f);
}
__device__ __forceinline__ float d2x(const float* __restrict__ w, int i, int j, float cc) {
    return (-(ldz(w,i+2,j)+ldz(w,i-2,j)) + 16.f*(ldz(w,i+1,j)+ldz(w,i-1,j)) - 30.f*cc) * (1.f/300.f);
}
__device__ __forceinline__ float d2y(const float* __restrict__ w, int i, int j, float cc) {
    return (-(ldz(w,i,j+2)+ldz(w,i,j-2)) + 16.f*(ldz(w,i,j+1)+ldz(w,i,j-1)) - 30.f*cc) * (1.f/300.f);
}
__device__ __forceinline__ void prof1(int x, int n, float d, float vmax, float* a, float* b) {
    float fl = fminf(fmaxf((float)(2 + 20 - x)/20.f, 0.f), 1.f);
    float fh = fminf(fmaxf((float)(x - (n - 23))/20.f, 0.f), 1.f);
    float fr = fmaxf(fl, fh);
    float sigma = 3.f*vmax*logf(1000.f)/(2.f*20.f*d)*fr*fr;
    float alpha = 3.14159265358979f*25.f*(1.f - fr);
    float bb = expf(-(sigma+alpha)*DTF);
    *a = sigma/(sigma+alpha+1e-9f)*(bb-1.f);
    *b = bb;
}

// Fused per-cell update (verified rounds 2/4/5/6/7) — used by fallback path.
__device__ __forceinline__ void cell_update(
    int c, int t,
    const float* __restrict__ wcb, float* __restrict__ wpb,
    const float* __restrict__ sccb, float* __restrict__ scpb,
    const float* __restrict__ pxc, float* __restrict__ pxn,
    const float* __restrict__ pyc, float* __restrict__ pyn,
    const float* __restrict__ pxsc, float* __restrict__ pxsn,
    const float* __restrict__ pysc, float* __restrict__ pysn,
    float* __restrict__ zx, float* __restrict__ zy,
    float* __restrict__ zxs, float* __restrict__ zys,
    const float* __restrict__ v2, const float* __restrict__ st,
    const float* __restrict__ axv, const float* __restrict__ bxv,
    const float* __restrict__ ayv, const float* __restrict__ byv,
    const float* __restrict__ amp, const int* __restrict__ sloc)
{
    int s = c / NCELL; int r = c - s*NCELL;
    int i = r / NYW;   int j = r - i*NYW;
    const float* w  = wcb  + s*NCELL;
    const float* ww = sccb + s*NCELL;

    float wcv  = ld3(&w[r]);
    float wscv = ld3(&ww[r]);

    float tx  = d2x(w,  i, j, wcv);
    float txs = d2x(ww, i, j, wscv);
    float ty  = d2y(w,  i, j, wcv);
    float tys = d2y(ww, i, j, wscv);

    int ib = xbi(i);
    int jb = ybi(j);

    if (i <= XBL+1 || i >= XBH-2) {
        float pv[5], pvs[5];
        #pragma unroll
        for (int k = 0; k < 5; ++k) {
            int ik = i + k - 2; int b = xbi(ik);
            float p = 0.f, ps = 0.f;
            if (b >= 0) {
                float bxk = bxv[ik], axk = axv[ik];
                int o = (s*NB + b)*NYW + j;
                p  = bxk*ld3(&pxc[o])  + axk*d1x(w,  ik, j);
                ps = bxk*ld3(&pxsc[o]) + axk*d1x(ww, ik, j);
            }
            pv[k] = p; pvs[k] = ps;
        }
        tx  += (8.f*(pv[3]-pv[1])  - (pv[4]-pv[0]))  * (1.f/60.f);
        txs += (8.f*(pvs[3]-pvs[1]) - (pvs[4]-pvs[0])) * (1.f/60.f);
        if (ib >= 0) {
            int o = (s*NB + ib)*NYW + j;
            st3(&pxn[o], pv[2]); st3(&pxsn[o], pvs[2]);
        }
    }

    if (j <= XBL+1 || j >= YBH-2) {
        float pv[5], pvs[5];
        #pragma unroll
        for (int k = 0; k < 5; ++k) {
            int jk = j + k - 2; int b = ybi(jk);
            float p = 0.f, ps = 0.f;
            if (b >= 0) {
                float byk = byv[jk], ayk = ayv[jk];
                int o = (s*NX + i)*NB + b;
                p  = byk*ld3(&pyc[o])  + ayk*d1y(w,  i, jk);
                ps = byk*ld3(&pysc[o]) + ayk*d1y(ww, i, jk);
            }
            pv[k] = p; pvs[k] = ps;
        }
        ty  += (8.f*(pv[3]-pv[1])  - (pv[4]-pv[0]))  * (1.f/60.f);
        tys += (8.f*(pvs[3]-pvs[1]) - (pvs[4]-pvs[0])) * (1.f/60.f);
        if (jb >= 0) {
            int o = (s*NX + i)*NB + jb;
            st3(&pyn[o], pv[2]); st3(&pysn[o], pvs[2]);
        }
    }

    float zxv = 0.f, zyv = 0.f, zxsv = 0.f, zysv = 0.f;
    if (ib >= 0) {
        int o = (s*NB + ib)*NYW + j;
        float bx = bxv[i], ax = axv[i];
        zxv  = bx*ld3(&zx[o])  + ax*tx;  st3(&zx[o],  zxv);
        zxsv = bx*ld3(&zxs[o]) + ax*txs; st3(&zxs[o], zxsv);
    }
    if (jb >= 0) {
        int o = (s*NX + i)*NB + jb;
        float by = byv[j], ay = ayv[j];
        zyv  = by*ld3(&zy[o])  + ay*ty;  st3(&zy[o],  zyv);
        zysv = by*ld3(&zys[o]) + ay*tys; st3(&zys[o], zysv);
    }

    float lap  = tx + zxv + ty + zyv;
    float laps = txs + zxsv + tys + zysv;
    float vd   = v2[r];
    float wn   = vd*lap + 2.f*wcv - ld3(&wpb[c]);
    if (i == sloc[s*2] + PADC && j == sloc[s*2+1] + PADC)
        wn += vd * amp[s*NTS + t];
    float wsn = vd*laps + 2.f*wscv - ld3(&scpb[c]) + st[r]*lap;
    st3(&wpb[c],  wn);
    st3(&scpb[c], wsn);
}

// ---- fenced global barrier (setup only; proven r5-r7) ----
__device__ __forceinline__ void fbar(unsigned* bar, int flg_off, int gen_off,
                                     int lb, int nblk, unsigned target) {
    __syncthreads();
    if (lb == 0) {
        for (int b = threadIdx.x; b < nblk; b += NTHR) {
            if (b != 0) {
                while (ldu(&bar[flg_off + b*16]) < target)
                    __builtin_amdgcn_s_sleep(1);
            }
        }
        __builtin_amdgcn_fence(__ATOMIC_ACQUIRE, "agent");
        __syncthreads();
        if (threadIdx.x == 0)
            __hip_atomic_store(&bar[gen_off], target, __ATOMIC_RELEASE,
                               __HIP_MEMORY_SCOPE_AGENT);
    } else {
        if (threadIdx.x == 0) {
            __hip_atomic_store(&bar[flg_off + lb*16], target, __ATOMIC_RELEASE,
                               __HIP_MEMORY_SCOPE_AGENT);
            while (ldu(&bar[gen_off]) < target)
                __builtin_amdgcn_s_sleep(2);
            __builtin_amdgcn_fence(__ATOMIC_ACQUIRE, "agent");
        }
        __syncthreads();
    }
}

// ---- fence-free per-shot barrier (time loop). Correctness: data moves via
// relaxed agent ld3/st3 (coherence point); __syncthreads drains each wave's
// vmcnt, so the relaxed flag store ordered after it is a release; the spin +
// control dependency orders subsequent coherence-point loads. No cache ops.
__device__ __forceinline__ void sbar(unsigned* bar, int flg, int gen,
                                     int lb, unsigned target) {
    __syncthreads();
    if (lb == 0) {
        for (int b = 1 + (int)threadIdx.x; b < SBLK; b += NTHR) {
            while (ldu(&bar[flg + b*16]) < target)
                __builtin_amdgcn_s_sleep(1);
        }
        __syncthreads();
        if (threadIdx.x == 0) {
            asm volatile("s_waitcnt vmcnt(0)" ::: "memory");
            stu(&bar[gen], target);
        }
        __syncthreads();
    } else {
        if (threadIdx.x == 0) {
            asm volatile("s_waitcnt vmcnt(0)" ::: "memory");
            stu(&bar[flg + lb*16], target);
            while (ldu(&bar[gen]) < target)
                __builtin_amdgcn_s_sleep(2);
        }
        __syncthreads();
    }
}

struct SimArgs {
    const float* v; const float* scat; const float* amp;
    const int* sloc; const int* rloc;
    float* out; float* ws;
};

// ================= persistent single-kernel path =================
__global__ __launch_bounds__(NTHR, 8) void k_sim(SimArgs A) {
    const int tid = blockIdx.x*NTHR + threadIdx.x;
    const int nth = NBLK*NTHR;
    const int s   = blockIdx.x / SBLK;          // shot partition
    const int lb  = blockIdx.x - s*SBLK;        // local block in partition
    const int lt  = lb*NTHR + threadIdx.x;      // local thread in partition

    unsigned* bar = (unsigned*)A.ws;
    unsigned* vmx = bar + VMXO;

    float* base = A.ws + BARF;
    const size_t F = (size_t)NTOT;
    float* wA   = base;
    float* wB   = wA + F;
    float* sA   = wB + F;
    float* sB   = sA + F;
    float* pxA  = sB + F;
    float* pxB  = pxA + PXSZ;
    float* pxsA = pxB + PXSZ;
    float* pxsB = pxsA + PXSZ;
    float* zx   = pxsB + PXSZ;
    float* zxs  = zx + PXSZ;
    float* pyA  = zxs + PXSZ;
    float* pyB  = pyA + PYSZ;
    float* pysA = pyB + PYSZ;
    float* pysB = pysA + PYSZ;
    float* zy   = pysB + PYSZ;
    float* zys  = zy + PYSZ;
    float* v2   = zys + PYSZ;
    float* st   = v2 + NCELL;
    float* axv  = st + NCELL;
    float* bxv  = axv + NX;
    float* ayv  = bxv + NX;
    float* byv  = ayv + NYW;

    // phase 0: zero recurrence state (barrier region zeroed by host memset)
    const size_t ZTOT = 4*F + 6*(size_t)PXSZ + 6*(size_t)PYSZ;
    for (size_t z = (size_t)tid; z < ZTOT; z += (size_t)nth) base[z] = 0.f;
    fbar(bar, GFLG, GGEN, blockIdx.x, NBLK, 1u);

    // phase 1: vmax
    {
        float m = 0.f;
        for (int idx = tid; idx < NZV*NYV; idx += nth) m = fmaxf(m, fabsf(A.v[idx]));
        __shared__ float sm[NTHR];
        sm[threadIdx.x] = m; __syncthreads();
        for (int o = NTHR/2; o > 0; o >>= 1) {
            if (threadIdx.x < o) sm[threadIdx.x] = fmaxf(sm[threadIdx.x], sm[threadIdx.x+o]);
            __syncthreads();
        }
        if (threadIdx.x == 0) atomicMax(vmx, __float_as_uint(sm[0]));
    }
    fbar(bar, GFLG, GGEN, blockIdx.x, NBLK, 2u);

    // phase 2: PML profiles + v2dt2/sterm
    {
        float vmax = __uint_as_float(ldu(vmx));
        if (tid < NX) prof1(tid, NX, 5.0f, vmax, &axv[tid], &bxv[tid]);
        else if (tid < NX + NYW) { int y = tid - NX; prof1(y, NYW, 5.0f, vmax, &ayv[y], &byv[y]); }
        for (int c = tid; c < NCELL; c += nth) {
            int i = c / NYW, j = c - (c / NYW)*NYW;
            int iz = min(max(i - PADC, 0), NZV-1);
            int iy = min(max(j - PADC, 0), NYV-1);
            float vv = A.v[iz*NYV + iy];
            v2[c] = vv*vv*(DTF*DTF);
            float sp = 0.f;
            if (i >= PADC && i < PADC+NZV && j >= PADC && j < PADC+NYV)
                sp = A.scat[(i-PADC)*NYV + (j-PADC)];
            st[c] = 2.f*vv*sp*(DTF*DTF);
        }
    }
    fbar(bar, GFLG, GGEN, blockIdx.x, NBLK, 3u);

    // ---- per-thread invariants for the time loop (one cell per thread)
    const int  r    = lt;                 // cell index within shot
    const bool act  = (r < NCELL);
    const int  sbase = s*NCELL;
    const int  sc    = sbase + r;
    int i = 0, j = 0, ib = -1, jb = -1;
    bool xband = false, yband = false, isrc = false;
    float vd = 0.f, stv = 0.f;
    if (act) {
        i = r / NYW; j = r - i*NYW;
        ib = xbi(i); jb = ybi(j);
        xband = (i <= XBL+1 || i >= XBH-2);
        yband = (j <= XBL+1 || j >= YBH-2);
        vd = v2[r]; stv = st[r];
        isrc = (i == A.sloc[s*2] + PADC && j == A.sloc[s*2+1] + PADC);
    }

    // time loop: one fence-free per-shot barrier per step
    float *wcb=wA, *wpb=wB, *sccb=sA, *scpb=sB;
    float *pxc=pxA, *pxn=pxB, *pxsc=pxsA, *pxsn=pxsB;
    float *pyc=pyA, *pyn=pyB, *pysc=pysA, *pysn=pysB;

    const int sflg = SFLG + s*SSTR;
    const int sgen = SGEN + s*16;

    for (int t = 0; t < NTS; ++t) {
        if (act) {
            const float* w  = wcb  + sbase;
            const float* ww = sccb + sbase;

            float wcv  = ld3(&w[r]);
            float wscv = ld3(&ww[r]);

            float tx  = d2x(w,  i, j, wcv);
            float txs = d2x(ww, i, j, wscv);
            float ty  = d2y(w,  i, j, wcv);
            float tys = d2y(ww, i, j, wscv);

            if (xband) {
                float pv[5], pvs[5];
                #pragma unroll
                for (int k = 0; k < 5; ++k) {
                    int ik = i + k - 2; int b = xbi(ik);
                    float p = 0.f, ps = 0.f;
                    if (b >= 0) {
                        float bxk = bxv[ik], axk = axv[ik];
                        int o = (s*NB + b)*NYW + j;
                        p  = bxk*ld3(&pxc[o])  + axk*d1x(w,  ik, j);
                        ps = bxk*ld3(&pxsc[o]) + axk*d1x(ww, ik, j);
                    }
                    pv[k] = p; pvs[k] = ps;
                }
                tx  += (8.f*(pv[3]-pv[1])  - (pv[4]-pv[0]))  * (1.f/60.f);
                txs += (8.f*(pvs[3]-pvs[1]) - (pvs[4]-pvs[0])) * (1.f/60.f);
                if (ib >= 0) {
                    int o = (s*NB + ib)*NYW + j;
                    st3(&pxn[o], pv[2]); st3(&pxsn[o], pvs[2]);
                }
            }

            if (yband) {
                float pv[5], pvs[5];
                #pragma unroll
                for (int k = 0; k < 5; ++k) {
                    int jk = j + k - 2; int b = ybi(jk);
                    float p = 0.f, ps = 0.f;
                    if (b >= 0) {
                        float byk = byv[jk], ayk = ayv[jk];
                        int o = (s*NX + i)*NB + b;
                        p  = byk*ld3(&pyc[o])  + ayk*d1y(w,  i, jk);
                        ps = byk*ld3(&pysc[o]) + ayk*d1y(ww, i, jk);
                    }
                    pv[k] = p; pvs[k] = ps;
                }
                ty  += (8.f*(pv[3]-pv[1])  - (pv[4]-pv[0]))  * (1.f/60.f);
                tys += (8.f*(pvs[3]-pvs[1]) - (pvs[4]-pvs[0])) * (1.f/60.f);
                if (jb >= 0) {
                    int o = (s*NX + i)*NB + jb;
                    st3(&pyn[o], pv[2]); st3(&pysn[o], pvs[2]);
                }
            }

            float zxv = 0.f, zyv = 0.f, zxsv = 0.f, zysv = 0.f;
            if (ib >= 0) {
                int o = (s*NB + ib)*NYW + j;
                float bx = bxv[i], ax = axv[i];
                zxv  = bx*ld3(&zx[o])  + ax*tx;  st3(&zx[o],  zxv);
                zxsv = bx*ld3(&zxs[o]) + ax*txs; st3(&zxs[o], zxsv);
            }
            if (jb >= 0) {
                int o = (s*NX + i)*NB + jb;
                float by = byv[j], ay = ayv[j];
                zyv  = by*ld3(&zy[o])  + ay*ty;  st3(&zy[o],  zyv);
                zysv = by*ld3(&zys[o]) + ay*tys; st3(&zys[o], zysv);
            }

            float lap  = tx + zxv + ty + zyv;
            float laps = txs + zxsv + tys + zysv;
            float wn   = vd*lap + 2.f*wcv - ld3(&wpb[sc]);
            if (isrc) wn += vd * A.amp[s*NTS + t];
            float wsn = vd*laps + 2.f*wscv - ld3(&scpb[sc]) + stv*lap;
            st3(&wpb[sc],  wn);
            st3(&scpb[sc], wsn);
        }
        sbar(bar, sflg, sgen, lb, (unsigned)(t+1));

        // gather: reads just-written scpb; next step only READS that buffer.
        if (lt < NRECV) {
            int ri = A.rloc[(s*NRECV+lt)*2+0] + PADC;
            int rj = A.rloc[(s*NRECV+lt)*2+1] + PADC;
            A.out[(s*NRECV+lt)*NTS + t] = ld3(&scpb[sbase + ri*NYW + rj]);
        }

        float* tm;
        tm=wcb;  wcb=wpb;   wpb=tm;
        tm=sccb; sccb=scpb; scpb=tm;
        tm=pxc;  pxc=pxn;   pxn=tm;
        tm=pyc;  pyc=pyn;   pyn=tm;
        tm=pxsc; pxsc=pxsn; pxsn=tm;
        tm=pysc; pysc=pysn; pysn=tm;
    }
}

// ================= fallback multi-kernel path (verified round-2) =================
__global__ void k_vmax(const float* __restrict__ v, unsigned* __restrict__ vmx) {
    __shared__ float sm[256];
    float m = 0.f;
    for (int idx = blockIdx.x*256 + threadIdx.x; idx < NZV*NYV; idx += gridDim.x*256)
        m = fmaxf(m, fabsf(v[idx]));
    sm[threadIdx.x] = m; __syncthreads();
    for (int o = 128; o > 0; o >>= 1) {
        if (threadIdx.x < o) sm[threadIdx.x] = fmaxf(sm[threadIdx.x], sm[threadIdx.x+o]);
        __syncthreads();
    }
    if (threadIdx.x == 0) atomicMax(vmx, __float_as_uint(sm[0]));
}

__global__ void k_prep(const float* __restrict__ v, const float* __restrict__ sc,
                       float* __restrict__ v2dt2, float* __restrict__ sterm) {
    int c = blockIdx.x*blockDim.x + threadIdx.x;
    if (c >= NCELL) return;
    int i = c / NYW, j = c - (c / NYW)*NYW;
    int iz = min(max(i - PADC, 0), NZV-1);
    int iy = min(max(j - PADC, 0), NYV-1);
    float vv = v[iz*NYV + iy];
    v2dt2[c] = vv*vv*(DTF*DTF);
    float sp = 0.f;
    if (i >= PADC && i < PADC+NZV && j >= PADC && j < PADC+NYV)
        sp = sc[(i-PADC)*NYV + (j-PADC)];
    sterm[c] = 2.f*vv*sp*(DTF*DTF);
}

__global__ void k_prof(const unsigned* __restrict__ vmx,
                       float* __restrict__ axv, float* __restrict__ bxv,
                       float* __restrict__ ayv, float* __restrict__ byv) {
    int x = threadIdx.x;
    float vmax = __uint_as_float(vmx[0]);
    if (x < NX)  prof1(x, NX,  5.0f, vmax, &axv[x], &bxv[x]);
    if (x < NYW) prof1(x, NYW, 5.0f, vmax, &ayv[x], &byv[x]);
}

__global__ __launch_bounds__(256) void k_fstep(
    const float* __restrict__ wf,   float* __restrict__ wold,
    const float* __restrict__ wsf,  float* __restrict__ wsold,
    const float* __restrict__ pxo,  float* __restrict__ pxn,
    const float* __restrict__ pyo,  float* __restrict__ pyn,
    const float* __restrict__ pxso, float* __restrict__ pxsn,
    const float* __restrict__ pyso, float* __restrict__ pysn,
    float* __restrict__ zx,  float* __restrict__ zy,
    float* __restrict__ zxs, float* __restrict__ zys,
    const float* __restrict__ v2, const float* __restrict__ st,
    const float* __restrict__ axv, const float* __restrict__ bxv,
    const float* __restrict__ ayv, const float* __restrict__ byv,
    const float* __restrict__ amp, const int* __restrict__ sloc,
    const int* __restrict__ rloc, float* __restrict__ out, int t)
{
    int bid = blockIdx.x;
    if (bid >= NSB) {
        if (t == 0) return;
        int g = (bid - NSB)*256 + threadIdx.x;
        if (g >= NSHOT*NRECV) return;
        int s = g / NRECV, rr = g - s*NRECV;
        int ri = rloc[(s*NRECV+rr)*2+0] + PADC;
        int rj = rloc[(s*NRECV+rr)*2+1] + PADC;
        out[(s*NRECV+rr)*NTS + (t-1)] = wsf[s*NCELL + ri*NYW + rj];
        return;
    }
    int c = bid*256 + threadIdx.x;
    if (c >= NTOT) return;
    cell_update(c, t, wf, wold, wsf, wsold,
                pxo, pxn, pyo, pyn, pxso, pxsn, pyso, pysn,
                zx, zy, zxs, zys, v2, st, axv, bxv, ayv, byv, amp, sloc);
}

__global__ void k_gtail(const float* __restrict__ wsn, const int* __restrict__ rloc,
                        float* __restrict__ out) {
    int g = blockIdx.x*blockDim.x + threadIdx.x;
    if (g >= NSHOT*NRECV) return;
    int s = g / NRECV, rr = g - s*NRECV;
    int ri = rloc[(s*NRECV+rr)*2+0] + PADC;
    int rj = rloc[(s*NRECV+rr)*2+1] + PADC;
    out[(s*NRECV+rr)*NTS + (NTS-1)] = wsn[s*NCELL + ri*NYW + rj];
}

extern "C" void kernel_launch(void* const* d_in, const int* in_sizes, int n_in,
                              void* d_out, int out_size, void* d_ws, size_t ws_size,
                              hipStream_t stream) {
    const float* v    = (const float*)d_in[0];
    const float* scat = (const float*)d_in[1];
    const float* amp  = (const float*)d_in[2];
    const int*   sloc = (const int*)d_in[3];
    const int*   rloc = (const int*)d_in[4];
    float* out = (float*)d_out;
    float* ws  = (float*)d_ws;

    SimArgs args;
    args.v = v; args.scat = scat; args.amp = amp;
    args.sloc = sloc; args.rloc = rloc;
    args.out = out; args.ws = ws;

    // zero barrier flags + gens + vmax accumulator
    hipMemsetAsync(ws, 0, BARF*sizeof(float), stream);

    void* kargs[] = { &args };
    hipError_t e = hipLaunchCooperativeKernel((const void*)k_sim, dim3(NBLK), dim3(NTHR),
                                              kargs, 0, stream);
    if (e == hipSuccess) return;

    // ---- fallback: verified multi-kernel path
    float* base = ws + BARF;
    const size_t F = (size_t)NTOT;
    float* wA   = base;
    float* wB   = wA + F;
    float* sA   = wB + F;
    float* sB   = sA + F;
    float* pxA  = sB + F;
    float* pxB  = pxA + PXSZ;
    float* pxsA = pxB + PXSZ;
    float* pxsB = pxsA + PXSZ;
    float* zx   = pxsB + PXSZ;
    float* zxs  = zx + PXSZ;
    float* pyA  = zxs + PXSZ;
    float* pyB  = pyA + PYSZ;
    float* pysA = pyB + PYSZ;
    float* pysB = pysA + PYSZ;
    float* zy   = pysB + PYSZ;
    float* zys  = zy + PYSZ;
    float* v2   = zys + PYSZ;
    float* st   = v2 + NCELL;
    float* axv  = st + NCELL;
    float* bxv  = axv + NX;
    float* ayv  = bxv + NX;
    float* byv  = ayv + NYW;
    unsigned* vmx = (unsigned*)ws + VMXO;

    size_t zero_floats = 4*F + 6*(size_t)PXSZ + 6*(size_t)PYSZ;
    hipMemsetAsync(base, 0, zero_floats*sizeof(float), stream);

    hipLaunchKernelGGL(k_vmax, dim3(64), dim3(256), 0, stream, v, vmx);
    hipLaunchKernelGGL(k_prep, dim3((NCELL+255)/256), dim3(256), 0, stream, v, scat, v2, st);
    hipLaunchKernelGGL(k_prof, dim3(1), dim3(512), 0, stream, vmx, axv, bxv, ayv, byv);

    float* wc  = wA;  float* wp  = wB;
    float* scc = sA;  float* scp = sB;
    float* pxc = pxA; float* pxn = pxB;
    float* pyc = pyA; float* pyn = pyB;
    float* pxsc = pxsA; float* pxsn = pxsB;
    float* pysc = pysA; float* pysn = pysB;

    for (int t = 0; t < NTS; ++t) {
        hipLaunchKernelGGL(k_fstep, dim3(NSB + GB), dim3(256), 0, stream,
                           wc, wp, scc, scp,
                           pxc, pxn, pyc, pyn, pxsc, pxsn, pysc, pysn,
                           zx, zy, zxs, zys,
                           v2, st, axv, bxv, ayv, byv,
                           amp, sloc, rloc, out, t);
        float* tmp;
        tmp = wc;  wc  = wp;  wp  = tmp;
        tmp = scc; scc = scp; scp = tmp;
        tmp = pxc; pxc = pxn; pxn = tmp;
        tmp = pyc; pyc = pyn; pyn = tmp;
        tmp = pxsc; pxsc = pxsn; pxsn = tmp;
        tmp = pysc; pysc = pysn; pysn = tmp;
    }
    hipLaunchKernelGGL(k_gtail, dim3(2), dim3(256), 0, stream, scc, rloc, out);
}

// Round 9
// 1297.632 us; speedup vs baseline: 1.3913x; 1.3913x over previous
//
#include <hip/hip_runtime.h>

#define DTF   0.001f
#define NZV   250
#define NYV   350
#define NX    294          // 250 + 44
#define NYW   394          // 350 + 44
#define PADC  22
#define NSHOT 4
#define NTS   48
#define NRECV 100
#define NCELL (NX*NYW)     // 115836
#define NTOT  (NSHOT*NCELL)
#define XBL   22           // x in [0,21] is low band
#define XBH   (NX-22)      // 272
#define YBH   (NYW-22)     // 372
#define NB    44
#define PXSZ  (NSHOT*NB*NYW)
#define PYSZ  (NSHOT*NX*NB)
#define NTHR  256
#define NJG   99                   // ceil(NYW/4)
#define WITEMS (NSHOT*NX*NJG)      // 116424
#define NSB2  ((WITEMS+255)/256)   // 455
#define GB    2
#define BARF  1024                 // header floats (vmx at [0])

__device__ __forceinline__ int xbi(int i) {
    return ((unsigned)i < XBL) ? i : ((i >= XBH && i < NX) ? i-(NX-NB) : -1);
}
__device__ __forceinline__ int ybi(int j) {
    return ((unsigned)j < XBL) ? j : ((j >= YBH && j < NYW) ? j-(NYW-NB) : -1);
}
__device__ __forceinline__ float ldz(const float* __restrict__ w, int i, int j) {
    return ((unsigned)i < (unsigned)NX && (unsigned)j < (unsigned)NYW) ? w[i*NYW + j] : 0.f;
}
__device__ __forceinline__ void prof1(int x, int n, float d, float vmax, float* a, float* b) {
    float fl = fminf(fmaxf((float)(2 + 20 - x)/20.f, 0.f), 1.f);
    float fh = fminf(fmaxf((float)(x - (n - 23))/20.f, 0.f), 1.f);
    float fr = fmaxf(fl, fh);
    float sigma = 3.f*vmax*logf(1000.f)/(2.f*20.f*d)*fr*fr;
    float alpha = 3.14159265358979f*25.f*(1.f - fr);
    float bb = expf(-(sigma+alpha)*DTF);
    *a = sigma/(sigma+alpha+1e-9f)*(bb-1.f);
    *b = bb;
}

// ---------------- setup kernels (verified r2) ----------------
__global__ void k_vmax(const float* __restrict__ v, unsigned* __restrict__ vmx) {
    __shared__ float sm[256];
    float m = 0.f;
    for (int idx = blockIdx.x*256 + threadIdx.x; idx < NZV*NYV; idx += gridDim.x*256)
        m = fmaxf(m, fabsf(v[idx]));
    sm[threadIdx.x] = m; __syncthreads();
    for (int o = 128; o > 0; o >>= 1) {
        if (threadIdx.x < o) sm[threadIdx.x] = fmaxf(sm[threadIdx.x], sm[threadIdx.x+o]);
        __syncthreads();
    }
    if (threadIdx.x == 0) atomicMax(vmx, __float_as_uint(sm[0]));
}

__global__ void k_prep(const float* __restrict__ v, const float* __restrict__ sc,
                       float* __restrict__ v2dt2, float* __restrict__ sterm) {
    int c = blockIdx.x*blockDim.x + threadIdx.x;
    if (c >= NCELL) return;
    int i = c / NYW, j = c - (c / NYW)*NYW;
    int iz = min(max(i - PADC, 0), NZV-1);
    int iy = min(max(j - PADC, 0), NYV-1);
    float vv = v[iz*NYV + iy];
    v2dt2[c] = vv*vv*(DTF*DTF);
    float sp = 0.f;
    if (i >= PADC && i < PADC+NZV && j >= PADC && j < PADC+NYV)
        sp = sc[(i-PADC)*NYV + (j-PADC)];
    sterm[c] = 2.f*vv*sp*(DTF*DTF);
}

__global__ void k_prof(const unsigned* __restrict__ vmx,
                       float* __restrict__ axv, float* __restrict__ bxv,
                       float* __restrict__ ayv, float* __restrict__ byv) {
    int x = threadIdx.x;
    float vmax = __uint_as_float(vmx[0]);
    if (x < NX)  prof1(x, NX,  5.0f, vmax, &axv[x], &bxv[x]);
    if (x < NYW) prof1(x, NYW, 5.0f, vmax, &ayv[x], &byv[x]);
}

// ---------------- fused step, 4 cells/thread along y ----------------
__global__ __launch_bounds__(256) void k_fstep4(
    const float* __restrict__ wf,   float* __restrict__ wold,
    const float* __restrict__ wsf,  float* __restrict__ wsold,
    const float* __restrict__ pxo,  float* __restrict__ pxn,
    const float* __restrict__ pyo,  float* __restrict__ pyn,
    const float* __restrict__ pxso, float* __restrict__ pxsn,
    const float* __restrict__ pyso, float* __restrict__ pysn,
    float* __restrict__ zx,  float* __restrict__ zy,
    float* __restrict__ zxs, float* __restrict__ zys,
    const float* __restrict__ v2, const float* __restrict__ st,
    const float* __restrict__ axv, const float* __restrict__ bxv,
    const float* __restrict__ ayv, const float* __restrict__ byv,
    const float* __restrict__ amp, const int* __restrict__ sloc,
    const int* __restrict__ rloc, float* __restrict__ out, int t)
{
    int bid = blockIdx.x;
    if (bid >= NSB2) {
        // gather previous step's scattered output (wsf is input-only here)
        if (t == 0) return;
        int g = (bid - NSB2)*256 + threadIdx.x;
        if (g >= NSHOT*NRECV) return;
        int s = g / NRECV, rr = g - s*NRECV;
        int ri = rloc[(s*NRECV+rr)*2+0] + PADC;
        int rj = rloc[(s*NRECV+rr)*2+1] + PADC;
        out[(s*NRECV+rr)*NTS + (t-1)] = wsf[s*NCELL + ri*NYW + rj];
        return;
    }
    int g = bid*256 + threadIdx.x;
    if (g >= WITEMS) return;
    int s  = g / (NX*NJG);
    int rm = g - s*(NX*NJG);
    int i  = rm / NJG;
    int jg = rm - i*NJG;
    int j0 = jg*4;

    const float* w  = wf  + s*NCELL;
    const float* ww = wsf + s*NCELL;

    const bool ybt = (jg <= 5 || jg >= 92);

    // center row: cw[m] = w[i][j0-4+m], m=0..11 (only 2..9 filled if !ybt)
    float cw[12], cs[12];
    if (ybt) {
        #pragma unroll
        for (int m = 0; m < 12; ++m) { cw[m] = ldz(w, i, j0-4+m); cs[m] = ldz(ww, i, j0-4+m); }
    } else {
        cw[0]=cw[1]=cw[10]=cw[11]=0.f; cs[0]=cs[1]=cs[10]=cs[11]=0.f;
        #pragma unroll
        for (int m = 0; m < 8; ++m) { cw[2+m] = ldz(w, i, j0-2+m); cs[2+m] = ldz(ww, i, j0-2+m); }
    }
    // neighbor rows, 4 center columns
    float am2[4], am1[4], ap1[4], ap2[4], bm2[4], bm1[4], bp1[4], bp2[4];
    #pragma unroll
    for (int k = 0; k < 4; ++k) {
        int j = j0 + k;
        am2[k]=ldz(w,i-2,j); am1[k]=ldz(w,i-1,j); ap1[k]=ldz(w,i+1,j); ap2[k]=ldz(w,i+2,j);
        bm2[k]=ldz(ww,i-2,j); bm1[k]=ldz(ww,i-1,j); bp1[k]=ldz(ww,i+1,j); bp2[k]=ldz(ww,i+2,j);
    }

    float tx[4], ty[4], txs[4], tys[4];
    #pragma unroll
    for (int k = 0; k < 4; ++k) {
        tx[k]  = (-(ap2[k]+am2[k]) + 16.f*(ap1[k]+am1[k]) - 30.f*cw[k+4]) * (1.f/300.f);
        txs[k] = (-(bp2[k]+bm2[k]) + 16.f*(bp1[k]+bm1[k]) - 30.f*cs[k+4]) * (1.f/300.f);
        ty[k]  = (-(cw[k+6]+cw[k+2]) + 16.f*(cw[k+5]+cw[k+3]) - 30.f*cw[k+4]) * (1.f/300.f);
        tys[k] = (-(cs[k+6]+cs[k+2]) + 16.f*(cs[k+5]+cs[k+3]) - 30.f*cs[k+4]) * (1.f/300.f);
    }

    const int ib = xbi(i);
    // x-band PML: recompute p_new at i-2..i+2 per column
    if (i <= XBL+1 || i >= XBH-2) {
        #pragma unroll
        for (int k = 0; k < 4; ++k) {
            int j = j0 + k;
            if (j >= NYW) continue;
            float wx[9], wsx[9];
            #pragma unroll
            for (int m = 0; m < 9; ++m) { wx[m] = ldz(w, i-4+m, j); wsx[m] = ldz(ww, i-4+m, j); }
            float pv[5], pvs[5];
            #pragma unroll
            for (int kk = 0; kk < 5; ++kk) {
                int ik = i + kk - 2; int b = xbi(ik);
                float p = 0.f, ps = 0.f;
                if (b >= 0) {
                    float bxk = bxv[ik], axk = axv[ik];
                    int o = (s*NB + b)*NYW + j;
                    float d1  = (8.f*(wx[kk+3]-wx[kk+1])  - (wx[kk+4]-wx[kk]))  * (1.f/60.f);
                    float d1s = (8.f*(wsx[kk+3]-wsx[kk+1]) - (wsx[kk+4]-wsx[kk])) * (1.f/60.f);
                    p  = bxk*pxo[o]  + axk*d1;
                    ps = bxk*pxso[o] + axk*d1s;
                }
                pv[kk] = p; pvs[kk] = ps;
            }
            tx[k]  += (8.f*(pv[3]-pv[1])  - (pv[4]-pv[0]))  * (1.f/60.f);
            txs[k] += (8.f*(pvs[3]-pvs[1]) - (pvs[4]-pvs[0])) * (1.f/60.f);
            if (ib >= 0) {
                int o = (s*NB + ib)*NYW + j;
                pxn[o] = pv[2]; pxsn[o] = pvs[2];
            }
        }
    }

    // y-band PML per cell
    if (ybt) {
        #pragma unroll
        for (int k = 0; k < 4; ++k) {
            int j = j0 + k;
            if (j >= NYW) continue;
            if (j <= XBL+1 || j >= YBH-2) {
                float pv[5], pvs[5];
                #pragma unroll
                for (int m = 0; m < 5; ++m) {
                    int jk = j + m - 2; int b = ybi(jk);
                    float p = 0.f, ps = 0.f;
                    if (b >= 0) {
                        float byk = byv[jk], ayk = ayv[jk];
                        int o = (s*NX + i)*NB + b;
                        float d1  = (8.f*(cw[k+m+3]-cw[k+m+1]) - (cw[k+m+4]-cw[k+m])) * (1.f/60.f);
                        float d1s = (8.f*(cs[k+m+3]-cs[k+m+1]) - (cs[k+m+4]-cs[k+m])) * (1.f/60.f);
                        p  = byk*pyo[o]  + ayk*d1;
                        ps = byk*pyso[o] + ayk*d1s;
                    }
                    pv[m] = p; pvs[m] = ps;
                }
                ty[k]  += (8.f*(pv[3]-pv[1])  - (pv[4]-pv[0]))  * (1.f/60.f);
                tys[k] += (8.f*(pvs[3]-pvs[1]) - (pvs[4]-pvs[0])) * (1.f/60.f);
                int jb = ybi(j);
                if (jb >= 0) {
                    int o = (s*NX + i)*NB + jb;
                    pyn[o] = pv[2]; pysn[o] = pvs[2];
                }
            }
        }
    }

    // z updates + field update + source, per cell
    const int si = sloc[s*2] + PADC, sj = sloc[s*2+1] + PADC;
    #pragma unroll
    for (int k = 0; k < 4; ++k) {
        int j = j0 + k;
        if (j >= NYW) continue;
        int r = i*NYW + j;
        int c = s*NCELL + r;
        float zxv = 0.f, zxsv = 0.f;
        if (ib >= 0) {
            int o = (s*NB + ib)*NYW + j;
            float bx = bxv[i], ax = axv[i];
            zxv  = bx*zx[o]  + ax*tx[k];  zx[o]  = zxv;
            zxsv = bx*zxs[o] + ax*txs[k]; zxs[o] = zxsv;
        }
        float zyv = 0.f, zysv = 0.f;
        int jb = ybi(j);
        if (jb >= 0) {
            int o = (s*NX + i)*NB + jb;
            float by = byv[j], ay = ayv[j];
            zyv  = by*zy[o]  + ay*ty[k];  zy[o]  = zyv;
            zysv = by*zys[o] + ay*tys[k]; zys[o] = zysv;
        }
        float lap  = tx[k] + zxv + ty[k] + zyv;
        float laps = txs[k] + zxsv + tys[k] + zysv;
        float vd   = v2[r];
        float wn   = vd*lap + 2.f*cw[k+4] - wold[c];
        if (i == si && j == sj) wn += vd * amp[s*NTS + t];
        float wsn = vd*laps + 2.f*cs[k+4] - wsold[c] + st[r]*lap;
        wold[c]  = wn;
        wsold[c] = wsn;
    }
}

// ---------------- tail gather ----------------
__global__ void k_gtail(const float* __restrict__ wsn, const int* __restrict__ rloc,
                        float* __restrict__ out) {
    int g = blockIdx.x*blockDim.x + threadIdx.x;
    if (g >= NSHOT*NRECV) return;
    int s = g / NRECV, rr = g - s*NRECV;
    int ri = rloc[(s*NRECV+rr)*2+0] + PADC;
    int rj = rloc[(s*NRECV+rr)*2+1] + PADC;
    out[(s*NRECV+rr)*NTS + (NTS-1)] = wsn[s*NCELL + ri*NYW + rj];
}

extern "C" void kernel_launch(void* const* d_in, const int* in_sizes, int n_in,
                              void* d_out, int out_size, void* d_ws, size_t ws_size,
                              hipStream_t stream) {
    const float* v    = (const float*)d_in[0];
    const float* scat = (const float*)d_in[1];
    const float* amp  = (const float*)d_in[2];
    const int*   sloc = (const int*)d_in[3];
    const int*   rloc = (const int*)d_in[4];
    float* out = (float*)d_out;
    float* ws  = (float*)d_ws;

    float* base = ws + BARF;
    const size_t F = (size_t)NTOT;
    float* wA   = base;
    float* wB   = wA + F;
    float* sA   = wB + F;
    float* sB   = sA + F;
    float* pxA  = sB + F;
    float* pxB  = pxA + PXSZ;
    float* pxsA = pxB + PXSZ;
    float* pxsB = pxsA + PXSZ;
    float* zx   = pxsB + PXSZ;
    float* zxs  = zx + PXSZ;
    float* pyA  = zxs + PXSZ;
    float* pyB  = pyA + PYSZ;
    float* pysA = pyB + PYSZ;
    float* pysB = pysA + PYSZ;
    float* zy   = pysB + PYSZ;
    float* zys  = zy + PYSZ;
    float* v2   = zys + PYSZ;
    float* st   = v2 + NCELL;
    float* axv  = st + NCELL;
    float* bxv  = axv + NX;
    float* ayv  = bxv + NX;
    float* byv  = ayv + NYW;
    unsigned* vmx = (unsigned*)ws;

    // zero header (vmx) + all recurrence state
    size_t zero_floats = BARF + 4*F + 6*(size_t)PXSZ + 6*(size_t)PYSZ;
    hipMemsetAsync(ws, 0, zero_floats*sizeof(float), stream);

    hipLaunchKernelGGL(k_vmax, dim3(64), dim3(256), 0, stream, v, vmx);
    hipLaunchKernelGGL(k_prep, dim3((NCELL+255)/256), dim3(256), 0, stream, v, scat, v2, st);
    hipLaunchKernelGGL(k_prof, dim3(1), dim3(512), 0, stream, vmx, axv, bxv, ayv, byv);

    float* wc  = wA;  float* wp  = wB;
    float* scc = sA;  float* scp = sB;
    float* pxc = pxA; float* pxn = pxB;
    float* pyc = pyA; float* pyn = pyB;
    float* pxsc = pxsA; float* pxsn = pxsB;
    float* pysc = pysA; float* pysn = pysB;

    for (int t = 0; t < NTS; ++t) {
        hipLaunchKernelGGL(k_fstep4, dim3(NSB2 + GB), dim3(256), 0, stream,
                           wc, wp, scc, scp,
                           pxc, pxn, pyc, pyn, pxsc, pxsn, pysc, pysn,
                           zx, zy, zxs, zys,
                           v2, st, axv, bxv, ayv, byv,
                           amp, sloc, rloc, out, t);
        float* tmp;
        tmp = wc;  wc  = wp;  wp  = tmp;
        tmp = scc; scc = scp; scp = tmp;
        tmp = pxc; pxc = pxn; pxn = tmp;
        tmp = pyc; pyc = pyn; pyn = tmp;
        tmp = pxsc; pxsc = pxsn; pxsn = tmp;
        tmp = pysc; pysc = pysn; pysn = tmp;
    }
    hipLaunchKernelGGL(k_gtail, dim3(2), dim3(256), 0, stream, scc, rloc, out);
}

// Round 10
// 944.108 us; speedup vs baseline: 1.9123x; 1.3745x over previous
//
#include <hip/hip_runtime.h>

#define DTF   0.001f
#define NZV   250
#define NYV   350
#define NX    294          // 250 + 44
#define NYW   394          // 350 + 44
#define PADC  22
#define NSHOT 4
#define NTS   48
#define NRECV 100
#define NCELL (NX*NYW)     // 115836
#define NTOT  (NSHOT*NCELL)
#define XBL   22
#define XBH   (NX-22)      // 272
#define YBH   (NYW-22)     // 372
#define NB    44
#define PXSZ  (NSHOT*NB*NYW)
#define PYSZ  (NSHOT*NX*NB)
#define NSB   ((NTOT+255)/256) // fallback stencil blocks
#define GB    2
#define NTHR  256
#define HDRF  327680           // header floats (1.25 MB)

// header layout (uint offsets)
#define VMXO  0
#define CNT   16               // census: 8 x 16
#define GGEN  256
#define GFLG  512              // global fbar flags: up to 2048 x 16
#define TGEN  33536            // team gens: 8 x 16
#define TFLG  34048            // team flags: 8 x (2048 x 16)

__device__ __forceinline__ unsigned ldu(const unsigned* p) {
    return __hip_atomic_load(const_cast<unsigned*>(p), __ATOMIC_RELAXED,
                             __HIP_MEMORY_SCOPE_AGENT);
}
__device__ __forceinline__ void stu(unsigned* p, unsigned v) {
    __hip_atomic_store(p, v, __ATOMIC_RELAXED, __HIP_MEMORY_SCOPE_AGENT);
}

__device__ __forceinline__ int xbi(int i) {
    return ((unsigned)i < XBL) ? i : ((i >= XBH && i < NX) ? i-(NX-NB) : -1);
}
__device__ __forceinline__ int ybi(int j) {
    return ((unsigned)j < XBL) ? j : ((j >= YBH && j < NYW) ? j-(NYW-NB) : -1);
}
__device__ __forceinline__ float ldz(const float* __restrict__ w, int i, int j) {
    return ((unsigned)i < (unsigned)NX && (unsigned)j < (unsigned)NYW) ? w[i*NYW + j] : 0.f;
}
__device__ __forceinline__ float d1x(const float* __restrict__ w, int i, int j) {
    return (8.f*(ldz(w,i+1,j) - ldz(w,i-1,j)) - (ldz(w,i+2,j) - ldz(w,i-2,j))) * (1.f/60.f);
}
__device__ __forceinline__ float d1y(const float* __restrict__ w, int i, int j) {
    return (8.f*(ldz(w,i,j+1) - ldz(w,i,j-1)) - (ldz(w,i,j+2) - ldz(w,i,j-2))) * (1.f/60.f);
}
__device__ __forceinline__ float d2x(const float* __restrict__ w, int i, int j, float cc) {
    return (-(ldz(w,i+2,j)+ldz(w,i-2,j)) + 16.f*(ldz(w,i+1,j)+ldz(w,i-1,j)) - 30.f*cc) * (1.f/300.f);
}
__device__ __forceinline__ float d2y(const float* __restrict__ w, int i, int j, float cc) {
    return (-(ldz(w,i,j+2)+ldz(w,i,j-2)) + 16.f*(ldz(w,i,j+1)+ldz(w,i,j-1)) - 30.f*cc) * (1.f/300.f);
}
__device__ __forceinline__ void prof1(int x, int n, float d, float vmax, float* a, float* b) {
    float fl = fminf(fmaxf((float)(2 + 20 - x)/20.f, 0.f), 1.f);
    float fh = fminf(fmaxf((float)(x - (n - 23))/20.f, 0.f), 1.f);
    float fr = fmaxf(fl, fh);
    float sigma = 3.f*vmax*logf(1000.f)/(2.f*20.f*d)*fr*fr;
    float alpha = 3.14159265358979f*25.f*(1.f - fr);
    float bb = expf(-(sigma+alpha)*DTF);
    *a = sigma/(sigma+alpha+1e-9f)*(bb-1.f);
    *b = bb;
}

// per-cell update for the team path: shot-sliced pointers, v2/st recomputed
__device__ __forceinline__ void step_cell(
    int c, // cell index within shot
    const float* __restrict__ w,    float* __restrict__ wold,
    const float* __restrict__ ww,   float* __restrict__ wsold,
    const float* __restrict__ pxc,  float* __restrict__ pxn,
    const float* __restrict__ pyc,  float* __restrict__ pyn,
    const float* __restrict__ pxsc, float* __restrict__ pxsn,
    const float* __restrict__ pysc, float* __restrict__ pysn,
    float* __restrict__ zxS, float* __restrict__ zyS,
    float* __restrict__ zxsS, float* __restrict__ zysS,
    const float* __restrict__ vin, const float* __restrict__ scin,
    const float* __restrict__ axv, const float* __restrict__ bxv,
    const float* __restrict__ ayv, const float* __restrict__ byv,
    float av, int si, int sj)
{
    int i = c / NYW; int j = c - i*NYW;

    float wcv  = w[c];
    float wscv = ww[c];

    float tx  = d2x(w,  i, j, wcv);
    float txs = d2x(ww, i, j, wscv);
    float ty  = d2y(w,  i, j, wcv);
    float tys = d2y(ww, i, j, wscv);

    int ib = xbi(i);
    int jb = ybi(j);

    if (i <= XBL+1 || i >= XBH-2) {
        float pv[5], pvs[5];
        #pragma unroll
        for (int k = 0; k < 5; ++k) {
            int ik = i + k - 2; int b = xbi(ik);
            float p = 0.f, ps = 0.f;
            if (b >= 0) {
                float bxk = bxv[ik], axk = axv[ik];
                int o = b*NYW + j;
                p  = bxk*pxc[o]  + axk*d1x(w,  ik, j);
                ps = bxk*pxsc[o] + axk*d1x(ww, ik, j);
            }
            pv[k] = p; pvs[k] = ps;
        }
        tx  += (8.f*(pv[3]-pv[1])  - (pv[4]-pv[0]))  * (1.f/60.f);
        txs += (8.f*(pvs[3]-pvs[1]) - (pvs[4]-pvs[0])) * (1.f/60.f);
        if (ib >= 0) {
            int o = ib*NYW + j;
            pxn[o] = pv[2]; pxsn[o] = pvs[2];
        }
    }

    if (j <= XBL+1 || j >= YBH-2) {
        float pv[5], pvs[5];
        #pragma unroll
        for (int k = 0; k < 5; ++k) {
            int jk = j + k - 2; int b = ybi(jk);
            float p = 0.f, ps = 0.f;
            if (b >= 0) {
                float byk = byv[jk], ayk = ayv[jk];
                int o = i*NB + b;
                p  = byk*pyc[o]  + ayk*d1y(w,  i, jk);
                ps = byk*pysc[o] + ayk*d1y(ww, i, jk);
            }
            pv[k] = p; pvs[k] = ps;
        }
        ty  += (8.f*(pv[3]-pv[1])  - (pv[4]-pv[0]))  * (1.f/60.f);
        tys += (8.f*(pvs[3]-pvs[1]) - (pvs[4]-pvs[0])) * (1.f/60.f);
        if (jb >= 0) {
            int o = i*NB + jb;
            pyn[o] = pv[2]; pysn[o] = pvs[2];
        }
    }

    float zxv = 0.f, zyv = 0.f, zxsv = 0.f, zysv = 0.f;
    if (ib >= 0) {
        int o = ib*NYW + j;
        float bx = bxv[i], ax = axv[i];
        zxv  = bx*zxS[o]  + ax*tx;  zxS[o]  = zxv;
        zxsv = bx*zxsS[o] + ax*txs; zxsS[o] = zxsv;
    }
    if (jb >= 0) {
        int o = i*NB + jb;
        float by = byv[j], ay = ayv[j];
        zyv  = by*zyS[o]  + ay*ty;  zyS[o]  = zyv;
        zysv = by*zysS[o] + ay*tys; zysS[o] = zysv;
    }

    // recompute v2dt2/sterm from L2-resident inputs
    int iz = min(max(i - PADC, 0), NZV-1);
    int iy = min(max(j - PADC, 0), NYV-1);
    float vv = vin[iz*NYV + iy];
    float vd = vv*vv*(DTF*DTF);
    float stv = 0.f;
    if (i >= PADC && i < PADC+NZV && j >= PADC && j < PADC+NYV)
        stv = 2.f*vv*scin[(i-PADC)*NYV + (j-PADC)]*(DTF*DTF);

    float lap  = tx + zxv + ty + zyv;
    float laps = txs + zxsv + tys + zysv;
    float wn   = vd*lap + 2.f*wcv - wold[c];
    if (i == si && j == sj) wn += vd * av;
    float wsn = vd*laps + 2.f*wscv - wsold[c] + stv*lap;
    wold[c]  = wn;
    wsold[c] = wsn;
}

// ---- fenced global barrier (setup only; proven r5-r8) ----
__device__ __forceinline__ void fbar(unsigned* hdr, int lb, int nblk, unsigned target) {
    __syncthreads();
    if (lb == 0) {
        for (int b = threadIdx.x; b < nblk; b += NTHR) {
            if (b != 0) {
                while (ldu(&hdr[GFLG + b*16]) < target)
                    __builtin_amdgcn_s_sleep(1);
            }
        }
        __builtin_amdgcn_fence(__ATOMIC_ACQUIRE, "agent");
        __syncthreads();
        if (threadIdx.x == 0)
            __hip_atomic_store(&hdr[GGEN], target, __ATOMIC_RELEASE,
                               __HIP_MEMORY_SCOPE_AGENT);
    } else {
        if (threadIdx.x == 0) {
            __hip_atomic_store(&hdr[GFLG + lb*16], target, __ATOMIC_RELEASE,
                               __HIP_MEMORY_SCOPE_AGENT);
            while (ldu(&hdr[GGEN]) < target)
                __builtin_amdgcn_s_sleep(2);
            __builtin_amdgcn_fence(__ATOMIC_ACQUIRE, "agent");
        }
        __syncthreads();
    }
}

// ---- intra-XCD team barrier. Entry __syncthreads drains every wave's vmcnt
// (stores reach the XCD's shared L2 via write-through L1). Flags/gen are
// agent-scope atomics (bypass L1). After the barrier: invalidate L1 only
// (buffer_inv sc0) — L2 keeps the team's data, nothing goes to HBM.
__device__ __forceinline__ void tbar(unsigned* hdr, int xcd, int rank, int n,
                                     unsigned target) {
    __syncthreads();
    if (rank == 0) {
        int base = TFLG + xcd*32768;
        for (int b = 1 + (int)threadIdx.x; b < n; b += NTHR) {
            while (ldu(&hdr[base + b*16]) < target)
                __builtin_amdgcn_s_sleep(1);
        }
        __syncthreads();
        if (threadIdx.x == 0) stu(&hdr[TGEN + xcd*16], target);
    } else {
        if (threadIdx.x == 0) {
            stu(&hdr[TFLG + xcd*32768 + rank*16], target);
            while (ldu(&hdr[TGEN + xcd*16]) < target)
                __builtin_amdgcn_s_sleep(2);
        }
    }
    __syncthreads();
    asm volatile("buffer_inv sc0" ::: "memory");
}

struct SimArgs {
    const float* v; const float* scat; const float* amp;
    const int* sloc; const int* rloc;
    float* out; float* ws;
};

// ================= cooperative XCD-local path =================
__global__ __launch_bounds__(NTHR, 4) void k_sim2(SimArgs A) {
    unsigned* hdr = (unsigned*)A.ws;
    const int tidb = threadIdx.x;
    const int gtid = blockIdx.x*NTHR + tidb;
    const int nth  = gridDim.x*NTHR;

    // discover physical XCD and register in census
    __shared__ int sh_xcd, sh_rank;
    if (tidb == 0) {
        int x;
        asm volatile("s_getreg_b32 %0, hwreg(HW_REG_XCC_ID, 0, 32)" : "=s"(x));
        x &= 7;
        sh_xcd = x;
        sh_rank = (int)__hip_atomic_fetch_add(&hdr[CNT + x*16], 1u,
                                              __ATOMIC_RELAXED,
                                              __HIP_MEMORY_SCOPE_AGENT);
    }
    __syncthreads();
    const int xcd = sh_xcd;
    const int rank = sh_rank;

    float* base = A.ws + HDRF;
    const size_t F = (size_t)NTOT;
    float* wA   = base;
    float* wB   = wA + F;
    float* sA   = wB + F;
    float* sB   = sA + F;
    float* pxA  = sB + F;
    float* pxB  = pxA + PXSZ;
    float* pxsA = pxB + PXSZ;
    float* pxsB = pxsA + PXSZ;
    float* zx   = pxsB + PXSZ;
    float* zxs  = zx + PXSZ;
    float* pyA  = zxs + PXSZ;
    float* pyB  = pyA + PYSZ;
    float* pysA = pyB + PYSZ;
    float* pysB = pysA + PYSZ;
    float* zy   = pysB + PYSZ;
    float* zys  = zy + PYSZ;
    float* axv  = zys + PYSZ;
    float* bxv  = axv + NX;
    float* ayv  = bxv + NX;
    float* byv  = ayv + NYW;

    // phase 0: zero recurrence state
    const size_t ZTOT = 4*F + 6*(size_t)PXSZ + 6*(size_t)PYSZ;
    for (size_t z = (size_t)gtid; z < ZTOT; z += (size_t)nth) base[z] = 0.f;
    fbar(hdr, blockIdx.x, gridDim.x, 1u);

    // phase 1: vmax
    {
        float m = 0.f;
        for (int idx = gtid; idx < NZV*NYV; idx += nth) m = fmaxf(m, fabsf(A.v[idx]));
        __shared__ float sm[NTHR];
        sm[tidb] = m; __syncthreads();
        for (int o = NTHR/2; o > 0; o >>= 1) {
            if (tidb < o) sm[tidb] = fmaxf(sm[tidb], sm[tidb+o]);
            __syncthreads();
        }
        if (tidb == 0) atomicMax(&hdr[VMXO], __float_as_uint(sm[0]));
    }
    fbar(hdr, blockIdx.x, gridDim.x, 2u);

    // phase 2: PML profiles
    {
        float vmax = __uint_as_float(ldu(&hdr[VMXO]));
        if (gtid < NX) prof1(gtid, NX, 5.0f, vmax, &axv[gtid], &bxv[gtid]);
        else if (gtid < NX + NYW) { int y = gtid - NX; prof1(y, NYW, 5.0f, vmax, &ayv[y], &byv[y]); }
    }
    fbar(hdr, blockIdx.x, gridDim.x, 3u);

    const int n = (int)ldu(&hdr[CNT + xcd*16]);   // final census (post-fbar)
    if (xcd >= NSHOT) return;                     // spare XCDs idle
    const int s = xcd;

    // shot-sliced pointers (all mutable state for shot s stays in this XCD's L2)
    const size_t so = (size_t)s*NCELL;
    float *wcb = wA+so, *wpb = wB+so, *sccb = sA+so, *scpb = sB+so;
    float *pxc = pxA + s*(NB*NYW), *pxn = pxB + s*(NB*NYW);
    float *pxsc= pxsA+ s*(NB*NYW), *pxsn= pxsB+ s*(NB*NYW);
    float *zxS = zx  + s*(NB*NYW), *zxsS= zxs + s*(NB*NYW);
    float *pyc = pyA + s*(NX*NB),  *pyn = pyB + s*(NX*NB);
    float *pysc= pysA+ s*(NX*NB),  *pysn= pysB+ s*(NX*NB);
    float *zyS = zy  + s*(NX*NB),  *zysS= zys + s*(NX*NB);

    const int si = A.sloc[s*2] + PADC, sj = A.sloc[s*2+1] + PADC;
    const int stride = n*NTHR;
    const int c0 = rank*NTHR + tidb;

    for (int t = 0; t < NTS; ++t) {
        const float av = A.amp[s*NTS + t];
        for (int c = c0; c < NCELL; c += stride)
            step_cell(c, wcb, wpb, sccb, scpb,
                      pxc, pxn, pyc, pyn, pxsc, pxsn, pysc, pysn,
                      zxS, zyS, zxsS, zysS,
                      A.v, A.scat, axv, bxv, ayv, byv, av, si, sj);
        tbar(hdr, xcd, rank, n, (unsigned)(t+1));

        // gather by rank-0 block (scpb is read-only next step)
        if (rank == 0 && tidb < NRECV) {
            int ri = A.rloc[(s*NRECV+tidb)*2+0] + PADC;
            int rj = A.rloc[(s*NRECV+tidb)*2+1] + PADC;
            A.out[(s*NRECV+tidb)*NTS + t] = scpb[ri*NYW + rj];
        }

        float* tm;
        tm=wcb;  wcb=wpb;   wpb=tm;
        tm=sccb; sccb=scpb; scpb=tm;
        tm=pxc;  pxc=pxn;   pxn=tm;
        tm=pyc;  pyc=pyn;   pyn=tm;
        tm=pxsc; pxsc=pxsn; pxsn=tm;
        tm=pysc; pysc=pysn; pysn=tm;
    }
}

// ================= fallback multi-kernel path (verified r2, 603 us) =================
__device__ __forceinline__ void cell_update(
    int c, int t,
    const float* __restrict__ wcb, float* __restrict__ wpb,
    const float* __restrict__ sccb, float* __restrict__ scpb,
    const float* __restrict__ pxc, float* __restrict__ pxn,
    const float* __restrict__ pyc, float* __restrict__ pyn,
    const float* __restrict__ pxsc, float* __restrict__ pxsn,
    const float* __restrict__ pysc, float* __restrict__ pysn,
    float* __restrict__ zx, float* __restrict__ zy,
    float* __restrict__ zxs, float* __restrict__ zys,
    const float* __restrict__ vin, const float* __restrict__ scin,
    const float* __restrict__ axv, const float* __restrict__ bxv,
    const float* __restrict__ ayv, const float* __restrict__ byv,
    const float* __restrict__ amp, const int* __restrict__ sloc)
{
    int s = c / NCELL; int r = c - s*NCELL;
    step_cell(r, wcb + (size_t)s*NCELL, wpb + (size_t)s*NCELL,
              sccb + (size_t)s*NCELL, scpb + (size_t)s*NCELL,
              pxc + s*(NB*NYW), pxn + s*(NB*NYW),
              pyc + s*(NX*NB),  pyn + s*(NX*NB),
              pxsc + s*(NB*NYW), pxsn + s*(NB*NYW),
              pysc + s*(NX*NB),  pysn + s*(NX*NB),
              zx + s*(NB*NYW), zy + s*(NX*NB),
              zxs + s*(NB*NYW), zys + s*(NX*NB),
              vin, scin, axv, bxv, ayv, byv,
              amp[s*NTS + t], sloc[s*2] + PADC, sloc[s*2+1] + PADC);
}

__global__ void k_vmax(const float* __restrict__ v, unsigned* __restrict__ vmx) {
    __shared__ float sm[256];
    float m = 0.f;
    for (int idx = blockIdx.x*256 + threadIdx.x; idx < NZV*NYV; idx += gridDim.x*256)
        m = fmaxf(m, fabsf(v[idx]));
    sm[threadIdx.x] = m; __syncthreads();
    for (int o = 128; o > 0; o >>= 1) {
        if (threadIdx.x < o) sm[threadIdx.x] = fmaxf(sm[threadIdx.x], sm[threadIdx.x+o]);
        __syncthreads();
    }
    if (threadIdx.x == 0) atomicMax(vmx, __float_as_uint(sm[0]));
}

__global__ void k_prof(const unsigned* __restrict__ vmx,
                       float* __restrict__ axv, float* __restrict__ bxv,
                       float* __restrict__ ayv, float* __restrict__ byv) {
    int x = threadIdx.x;
    float vmax = __uint_as_float(vmx[0]);
    if (x < NX)  prof1(x, NX,  5.0f, vmax, &axv[x], &bxv[x]);
    if (x < NYW) prof1(x, NYW, 5.0f, vmax, &ayv[x], &byv[x]);
}

__global__ __launch_bounds__(256) void k_fstep(
    const float* __restrict__ wf,   float* __restrict__ wold,
    const float* __restrict__ wsf,  float* __restrict__ wsold,
    const float* __restrict__ pxo,  float* __restrict__ pxn,
    const float* __restrict__ pyo,  float* __restrict__ pyn,
    const float* __restrict__ pxso, float* __restrict__ pxsn,
    const float* __restrict__ pyso, float* __restrict__ pysn,
    float* __restrict__ zx,  float* __restrict__ zy,
    float* __restrict__ zxs, float* __restrict__ zys,
    const float* __restrict__ vin, const float* __restrict__ scin,
    const float* __restrict__ axv, const float* __restrict__ bxv,
    const float* __restrict__ ayv, const float* __restrict__ byv,
    const float* __restrict__ amp, const int* __restrict__ sloc,
    const int* __restrict__ rloc, float* __restrict__ out, int t)
{
    int bid = blockIdx.x;
    if (bid >= NSB) {
        if (t == 0) return;
        int g = (bid - NSB)*256 + threadIdx.x;
        if (g >= NSHOT*NRECV) return;
        int s = g / NRECV, rr = g - s*NRECV;
        int ri = rloc[(s*NRECV+rr)*2+0] + PADC;
        int rj = rloc[(s*NRECV+rr)*2+1] + PADC;
        out[(s*NRECV+rr)*NTS + (t-1)] = wsf[s*NCELL + ri*NYW + rj];
        return;
    }
    int c = bid*256 + threadIdx.x;
    if (c >= NTOT) return;
    cell_update(c, t, wf, wold, wsf, wsold,
                pxo, pxn, pyo, pyn, pxso, pxsn, pyso, pysn,
                zx, zy, zxs, zys, vin, scin, axv, bxv, ayv, byv, amp, sloc);
}

__global__ void k_gtail(const float* __restrict__ wsn, const int* __restrict__ rloc,
                        float* __restrict__ out) {
    int g = blockIdx.x*blockDim.x + threadIdx.x;
    if (g >= NSHOT*NRECV) return;
    int s = g / NRECV, rr = g - s*NRECV;
    int ri = rloc[(s*NRECV+rr)*2+0] + PADC;
    int rj = rloc[(s*NRECV+rr)*2+1] + PADC;
    out[(s*NRECV+rr)*NTS + (NTS-1)] = wsn[s*NCELL + ri*NYW + rj];
}

extern "C" void kernel_launch(void* const* d_in, const int* in_sizes, int n_in,
                              void* d_out, int out_size, void* d_ws, size_t ws_size,
                              hipStream_t stream) {
    const float* v    = (const float*)d_in[0];
    const float* scat = (const float*)d_in[1];
    const float* amp  = (const float*)d_in[2];
    const int*   sloc = (const int*)d_in[3];
    const int*   rloc = (const int*)d_in[4];
    float* out = (float*)d_out;
    float* ws  = (float*)d_ws;

    SimArgs args;
    args.v = v; args.scat = scat; args.amp = amp;
    args.sloc = sloc; args.rloc = rloc;
    args.out = out; args.ws = ws;

    // zero header (census, flags, gens, vmax) every call
    hipMemsetAsync(ws, 0, HDRF*sizeof(float), stream);

    int maxb = 0;
    int nblk = 0;
    if (hipOccupancyMaxActiveBlocksPerMultiprocessor(&maxb, (const void*)k_sim2,
                                                     NTHR, 0) == hipSuccess && maxb > 0) {
        long cap = (long)maxb * 256;          // 256 CUs
        nblk = (int)(cap < 2048 ? cap : 2048);
    }
    if (nblk >= 16) {
        void* kargs[] = { &args };
        hipError_t e = hipLaunchCooperativeKernel((const void*)k_sim2, dim3(nblk),
                                                  dim3(NTHR), kargs, 0, stream);
        if (e == hipSuccess) return;
    }

    // ---- fallback: verified multi-kernel path
    float* base = ws + HDRF;
    const size_t F = (size_t)NTOT;
    float* wA   = base;
    float* wB   = wA + F;
    float* sA   = wB + F;
    float* sB   = sA + F;
    float* pxA  = sB + F;
    float* pxB  = pxA + PXSZ;
    float* pxsA = pxB + PXSZ;
    float* pxsB = pxsA + PXSZ;
    float* zx   = pxsB + PXSZ;
    float* zxs  = zx + PXSZ;
    float* pyA  = zxs + PXSZ;
    float* pyB  = pyA + PYSZ;
    float* pysA = pyB + PYSZ;
    float* pysB = pysA + PYSZ;
    float* zy   = pysB + PYSZ;
    float* zys  = zy + PYSZ;
    float* axv  = zys + PYSZ;
    float* bxv  = axv + NX;
    float* ayv  = bxv + NX;
    float* byv  = ayv + NYW;
    unsigned* vmx = (unsigned*)ws + VMXO;

    size_t zero_floats = 4*F + 6*(size_t)PXSZ + 6*(size_t)PYSZ;
    hipMemsetAsync(base, 0, zero_floats*sizeof(float), stream);

    hipLaunchKernelGGL(k_vmax, dim3(64), dim3(256), 0, stream, v, vmx);
    hipLaunchKernelGGL(k_prof, dim3(1), dim3(512), 0, stream, vmx, axv, bxv, ayv, byv);

    float* wc  = wA;  float* wp  = wB;
    float* scc = sA;  float* scp = sB;
    float* pxc = pxA; float* pxn = pxB;
    float* pyc = pyA; float* pyn = pyB;
    float* pxsc = pxsA; float* pxsn = pxsB;
    float* pysc = pysA; float* pysn = pysB;

    for (int t = 0; t < NTS; ++t) {
        hipLaunchKernelGGL(k_fstep, dim3(NSB + GB), dim3(256), 0, stream,
                           wc, wp, scc, scp,
                           pxc, pxn, pyc, pyn, pxsc, pxsn, pysc, pysn,
                           zx, zy, zxs, zys,
                           v, scat, axv, bxv, ayv, byv,
                           amp, sloc, rloc, out, t);
        float* tmp;
        tmp = wc;  wc  = wp;  wp  = tmp;
        tmp = scc; scc = scp; scp = tmp;
        tmp = pxc; pxc = pxn; pxn = tmp;
        tmp = pyc; pyc = pyn; pyn = tmp;
        tmp = pxsc; pxsc = pxsn; pxsn = tmp;
        tmp = pysc; pysc = pysn; pysn = tmp;
    }
    hipLaunchKernelGGL(k_gtail, dim3(2), dim3(256), 0, stream, scc, rloc, out);
}